// Round 11
// baseline (380.417 us; speedup 1.0000x reference)
//
#include <hip/hip_runtime.h>
#include <cstdint>

// BFP quantize: block = channel vector at each (n,h,w), NCHW layout.
// N=64, C=256, H=W=56, mantissa_bits=3.
// delta = 2^(e-3), max_abs = m*2^e, m in [0.5,1) (frexp). q = trunc(x/delta)*delta.
// Exact pow2 arithmetic — absmax==0 verified R1..R10.
//
// R11: granule law (R1..R10): HBM-side granule >256B, <=1024B. Clean cases
// (FETCH/WRITE = 1.000x): R1 = 1024B per wave-instr; R7 = 256B per wave-instr
// but block's 4 ADJACENT waves formed 1024B on one CU. Dirty: R10 = 256B
// wave-runs paired only across blocks/XCDs (1.62x/2.25x); R8/R9 = scatter (3x).
// => Each wave instruction covers a full 1024B run (R1-proven clean even with
// neighboring runs in other blocks).
// Structure: block = 4 waves sharing one 64-float4 window (lane <-> float4
// site, 1024B run); wave w -> channels [w*64, w*64+64) (cross-wave split for
// occupancy, R10's win). Pass A 8-deep float4 batches: 8KB in flight/wave x
// 12.25 waves/CU ~ 98KB >> 22KB BDP (fixes R7's latency starvation). 4KB LDS
// + 1 barrier combine. Pass B: L3 re-read (R1/R7-proven), quantize, store.
// ~6% windows straddle plane boundaries (784 = 12.25*64) -> two >=256B runs,
// ~3% predicted overhead. 784 blocks x 256 thr = 3136 waves, all resident.

constexpr int C    = 256;
constexpr int HW   = 56 * 56;    // 3136
constexpr int HW4  = HW / 4;     // 784 float4 per (n,c) plane
constexpr int CHW4 = C * HW4;    // float4 per image
constexpr int WCH  = 64;         // channels per wave

__device__ __forceinline__ int fexp(float x) {
    int e;
    (void)frexpf(x, &e);         // v_frexp_exp_i32_f32; e=0 for x==0
    return e;
}

__device__ __forceinline__ void fmax4(float4& m, const float4& v) {
    m.x = fmaxf(m.x, fabsf(v.x));
    m.y = fmaxf(m.y, fabsf(v.y));
    m.z = fmaxf(m.z, fabsf(v.z));
    m.w = fmaxf(m.w, fabsf(v.w));
}

__global__ __launch_bounds__(256, 4)
void bfp_kernel(const float4* __restrict__ in, float4* __restrict__ out) {
    const int lane = threadIdx.x & 63;
    const int w    = threadIdx.x >> 6;          // wave = channel quarter
    const int sig  = blockIdx.x * 64 + lane;    // float4 site (all 4 waves same)
    const int n    = sig / HW4;
    const int s4   = sig - n * HW4;

    const float4* p = in  + (size_t)n * CHW4 + (size_t)w * WCH * HW4 + s4;
    float4*       q = out + (size_t)n * CHW4 + (size_t)w * WCH * HW4 + s4;

    // ---- pass A: abs-max over this wave's 64 channels (1024B run per instr) ----
    float4 a0 = make_float4(0.f, 0.f, 0.f, 0.f), a1 = a0, a2 = a0, a3 = a0;
#pragma unroll
    for (int i = 0; i < WCH; i += 8) {
        float4 x0 = p[(i + 0) * HW4], x1 = p[(i + 1) * HW4];
        float4 x2 = p[(i + 2) * HW4], x3 = p[(i + 3) * HW4];
        float4 x4 = p[(i + 4) * HW4], x5 = p[(i + 5) * HW4];
        float4 x6 = p[(i + 6) * HW4], x7 = p[(i + 7) * HW4];
        fmax4(a0, x0); fmax4(a1, x1); fmax4(a2, x2); fmax4(a3, x3);
        fmax4(a0, x4); fmax4(a1, x5); fmax4(a2, x6); fmax4(a3, x7);
    }
    float4 m;
    m.x = fmaxf(fmaxf(a0.x, a1.x), fmaxf(a2.x, a3.x));
    m.y = fmaxf(fmaxf(a0.y, a1.y), fmaxf(a2.y, a3.y));
    m.z = fmaxf(fmaxf(a0.z, a1.z), fmaxf(a2.z, a3.z));
    m.w = fmaxf(fmaxf(a0.w, a1.w), fmaxf(a2.w, a3.w));

    // ---- cross-wave combine: 4KB LDS, one barrier ----
    __shared__ float4 red[4][64];
    red[w][lane] = m;
    __syncthreads();
    float4 M = red[0][lane];
    fmax4(M, red[1][lane]);   // values already >=0; fabs harmless
    fmax4(M, red[2][lane]);
    fmax4(M, red[3][lane]);

    // ---- shared exponent -> delta = 2^(e-3), inv = 2^(3-e) (both exact) ----
    const int ex = fexp(M.x), ey = fexp(M.y), ez = fexp(M.z), ew = fexp(M.w);
    const float dx = ldexpf(1.f, ex - 3), ix = ldexpf(1.f, 3 - ex);
    const float dy = ldexpf(1.f, ey - 3), iy = ldexpf(1.f, 3 - ey);
    const float dz = ldexpf(1.f, ez - 3), iz = ldexpf(1.f, 3 - ez);
    const float dw = ldexpf(1.f, ew - 3), iw = ldexpf(1.f, 3 - ew);

    // ---- pass B: re-read own channels (L3-hit), quantize, 1024B-run stores ----
#pragma unroll
    for (int i = 0; i < WCH; i += 8) {
        float4 v[8];
#pragma unroll
        for (int k = 0; k < 8; ++k) v[k] = p[(i + k) * HW4];
#pragma unroll
        for (int k = 0; k < 8; ++k) {
            float4 r;
            r.x = truncf(v[k].x * ix) * dx;
            r.y = truncf(v[k].y * iy) * dy;
            r.z = truncf(v[k].z * iz) * dz;
            r.w = truncf(v[k].w * iw) * dw;
            q[(i + k) * HW4] = r;
        }
    }
}

extern "C" void kernel_launch(void* const* d_in, const int* in_sizes, int n_in,
                              void* d_out, int out_size, void* d_ws, size_t ws_size,
                              hipStream_t stream) {
    const float* in = (const float*)d_in[0];
    float* out      = (float*)d_out;
    int total4 = in_sizes[0] / (4 * C);   // 50176 float4 sites
    int blocks = total4 / 64;             // 784 windows of 64 float4 (exact)
    bfp_kernel<<<blocks, 256, 0, stream>>>((const float4*)in, (float4*)out);
}

// Round 12
// 283.547 us; speedup vs baseline: 1.3416x; 1.3416x over previous
//
#include <hip/hip_runtime.h>
#include <cstdint>

// BFP quantize: block = channel vector at each (n,h,w), NCHW layout.
// N=64, C=256, H=W=56, mantissa_bits=3.
// delta = 2^(e-3), max_abs = m*2^e, m in [0.5,1) (frexp). q = trunc(x/delta)*delta.
// Exact pow2 arithmetic — absmax==0 verified R1..R11.
//
// R12: CLEAN TEMPLATE (R1/R7: thread serially owns all 256 channels, block =
// contiguous site span) is the only geometry that measured FETCH/WRITE=1.000x.
// Every channel-split variant — lanes (R2/R8/R9) or waves (R10/R11) — amplified
// 1.6-3.6x regardless of per-instruction run size (64B..1024B). R7's defect is
// latency, not traffic: 3.53 TB/s = ~12KB in flight/CU vs ~90KB BDP (VGPR=32,
// compiler batched few loads). Fix ONLY the scheduling: explicit ping-pong
// 32/32 load batches (issue next 32 before reducing previous 32) -> steady
// ~24-32 outstanding x 12.25 waves/CU x 256B ~ 75-98KB/CU. Geometry (threads,
// addresses, runs) byte-identical to R7 so 1.000x traffic carries over.
// VGPR ~80 is free: grid-capped at 3.06 waves/SIMD (3136 waves / 256 CU).

constexpr int C   = 256;
constexpr int HW  = 56 * 56;     // 3136 (divisible by 64: waves stay in-image)
constexpr int CHW = C * HW;      // 802816

__device__ __forceinline__ int fexp(float x) {
    int e;
    (void)frexpf(x, &e);         // v_frexp_exp_i32_f32; e=0 for x==0
    return e;
}

// Load 32 consecutive channels (static indices; b is compile-time).
#define LOADB(arr, base)                                        \
    _Pragma("unroll")                                           \
    for (int k = 0; k < 32; ++k) arr[k] = p[((base) + k) * HW];

// Reduce 32 values into 4 accumulators (fmax with |.|; static indices).
#define REDB(arr)                                               \
    _Pragma("unroll")                                           \
    for (int k = 0; k < 32; k += 4) {                           \
        m0 = fmaxf(m0, fabsf(arr[k + 0]));                      \
        m1 = fmaxf(m1, fabsf(arr[k + 1]));                      \
        m2 = fmaxf(m2, fabsf(arr[k + 2]));                      \
        m3 = fmaxf(m3, fabsf(arr[k + 3]));                      \
    }

__global__ __launch_bounds__(256, 4)
void bfp_kernel(const float* __restrict__ in, float* __restrict__ out) {
    const int t = blockIdx.x * 256 + threadIdx.x;   // grid exact: 784*256
    const int n = t / HW;
    const int r = t - n * HW;

    const float* p = in  + (size_t)n * CHW + r;
    float*       q = out + (size_t)n * CHW + r;

    // ---- pass A: abs-max over 256 channels, hand software-pipelined ----
    float va[32], vb[32];
    float m0 = 0.f, m1 = 0.f, m2 = 0.f, m3 = 0.f;
    LOADB(va, 0)
    LOADB(vb, 32)  REDB(va)      // loads issue before the reduce consumes va
    LOADB(va, 64)  REDB(vb)
    LOADB(vb, 96)  REDB(va)
    LOADB(va, 128) REDB(vb)
    LOADB(vb, 160) REDB(va)
    LOADB(va, 192) REDB(vb)
    LOADB(vb, 224) REDB(va)
    REDB(vb)
    const float m = fmaxf(fmaxf(m0, m1), fmaxf(m2, m3));

    // ---- shared exponent -> delta = 2^(e-3), inv = 2^(3-e) (both exact) ----
    const int   e  = fexp(m);
    const float dq = ldexpf(1.f, e - 3);
    const float iq = ldexpf(1.f, 3 - e);

    // ---- pass B: re-read (L3-hit, proven R7), quantize, store ----
#pragma unroll
    for (int b = 0; b < 8; ++b) {
        float v[32];
#pragma unroll
        for (int k = 0; k < 32; ++k) v[k] = p[(b * 32 + k) * HW];
#pragma unroll
        for (int k = 0; k < 32; ++k) q[(b * 32 + k) * HW] = truncf(v[k] * iq) * dq;
    }
}

extern "C" void kernel_launch(void* const* d_in, const int* in_sizes, int n_in,
                              void* d_out, int out_size, void* d_ws, size_t ws_size,
                              hipStream_t stream) {
    const float* in = (const float*)d_in[0];
    float* out      = (float*)d_out;
    int total  = in_sizes[0] / C;          // 200704 scalar sites = N*HW
    int blocks = total / 256;              // 784 blocks, exact, fully resident
    bfp_kernel<<<blocks, 256, 0, stream>>>(in, out);
}

// Round 13
// 109.497 us; speedup vs baseline: 3.4742x; 2.5895x over previous
//
#include <hip/hip_runtime.h>
#include <cstdint>

// BFP quantize: block = channel vector at each (n,h,w), NCHW layout.
// N=64, C=256, H=W=56, mantissa_bits=3.
// delta = 2^(e-3), max_abs = m*2^e, m in [0.5,1) (frexp). q = trunc(x/delta)*delta.
// Exact pow2 arithmetic — absmax==0 verified R1..R12.
//
// R13: laws from 12 rounds of counters:
//  (1) traffic clean (FETCH/WRITE=1.000x) ONLY in the serial-channel template
//      (thread owns its channels serially, block = contiguous >=1KB site span,
//      waves sweep in-phase): R1/R7/R12. Every lane/wave channel-split: 1.6-3.6x.
//  (2) within the template, BW is latency-bound by wave count (R7: 3136 waves
//      grid-cap -> 3.5 TB/s); per-thread ILP is compiler-capped (R12: VGPR=64
//      refusal, 283us).
// Fix: TLP via TWO SEQUENTIAL KERNELS + workspace; channel split across TIME,
// never across concurrent streams. k_max part p: thread t sweeps channels
// [64p,64p+64) serially (16-load batches, R7-proven shape), partial max ->
// ws[p*SITES+t]. Grid (784,4) = 12544 waves = 49/CU work, 32/CU resident
// (4x R7). Parts touch disjoint channel planes -> no granule interaction.
// k_quant: read 4 partials (L2/L3), delta, re-read own 64 channels (L3:
// reuse ~200MB < 256MB, R1/R7-proven), quantize, store.

constexpr int C     = 256;
constexpr int HW    = 56 * 56;      // 3136
constexpr int CHW   = C * HW;       // 802816
constexpr int SITES = 64 * HW;      // 200704 spatial sites (N*HW)

__device__ __forceinline__ int fexp(float x) {
    int e;
    (void)frexpf(x, &e);            // v_frexp_exp_i32_f32; e=0 for x==0
    return e;
}

template <int P>
__global__ __launch_bounds__(256, 8)
void k_max(const float* __restrict__ in, float* __restrict__ ws) {
    constexpr int CPT = C / P;      // channels per thread
    const int t = blockIdx.x * 256 + threadIdx.x;   // site (grid exact)
    const int p = blockIdx.y;                       // channel part
    const int n = t / HW;
    const int r = t - n * HW;
    const float* src = in + (size_t)n * CHW + (size_t)p * CPT * HW + r;

    float m0 = 0.f, m1 = 0.f, m2 = 0.f, m3 = 0.f;
#pragma unroll
    for (int c = 0; c < CPT; c += 16) {             // 16-load batches (R7/R10 shape)
        float x0 = src[(c +  0) * HW], x1 = src[(c +  1) * HW];
        float x2 = src[(c +  2) * HW], x3 = src[(c +  3) * HW];
        float x4 = src[(c +  4) * HW], x5 = src[(c +  5) * HW];
        float x6 = src[(c +  6) * HW], x7 = src[(c +  7) * HW];
        float x8 = src[(c +  8) * HW], x9 = src[(c +  9) * HW];
        float xa = src[(c + 10) * HW], xb = src[(c + 11) * HW];
        float xc = src[(c + 12) * HW], xd = src[(c + 13) * HW];
        float xe = src[(c + 14) * HW], xf = src[(c + 15) * HW];
        m0 = fmaxf(m0, fabsf(x0)); m1 = fmaxf(m1, fabsf(x1));
        m2 = fmaxf(m2, fabsf(x2)); m3 = fmaxf(m3, fabsf(x3));
        m0 = fmaxf(m0, fabsf(x4)); m1 = fmaxf(m1, fabsf(x5));
        m2 = fmaxf(m2, fabsf(x6)); m3 = fmaxf(m3, fabsf(x7));
        m0 = fmaxf(m0, fabsf(x8)); m1 = fmaxf(m1, fabsf(x9));
        m2 = fmaxf(m2, fabsf(xa)); m3 = fmaxf(m3, fabsf(xb));
        m0 = fmaxf(m0, fabsf(xc)); m1 = fmaxf(m1, fabsf(xd));
        m2 = fmaxf(m2, fabsf(xe)); m3 = fmaxf(m3, fabsf(xf));
    }
    ws[(size_t)p * SITES + t] = fmaxf(fmaxf(m0, m1), fmaxf(m2, m3));
}

template <int P>
__global__ __launch_bounds__(256, 8)
void k_quant(const float* __restrict__ in, float* __restrict__ out,
             const float* __restrict__ ws) {
    constexpr int CPT = C / P;
    const int t = blockIdx.x * 256 + threadIdx.x;
    const int p = blockIdx.y;

    float m = ws[t];
#pragma unroll
    for (int pp = 1; pp < P; ++pp) m = fmaxf(m, ws[(size_t)pp * SITES + t]);

    const int   e  = fexp(m);
    const float dq = ldexpf(1.f, e - 3);
    const float iq = ldexpf(1.f, 3 - e);

    const int n = t / HW;
    const int r = t - n * HW;
    const float* src = in  + (size_t)n * CHW + (size_t)p * CPT * HW + r;
    float*       dst = out + (size_t)n * CHW + (size_t)p * CPT * HW + r;

#pragma unroll
    for (int c = 0; c < CPT; c += 8) {
        float v0 = src[(c + 0) * HW], v1 = src[(c + 1) * HW];
        float v2 = src[(c + 2) * HW], v3 = src[(c + 3) * HW];
        float v4 = src[(c + 4) * HW], v5 = src[(c + 5) * HW];
        float v6 = src[(c + 6) * HW], v7 = src[(c + 7) * HW];
        dst[(c + 0) * HW] = truncf(v0 * iq) * dq;
        dst[(c + 1) * HW] = truncf(v1 * iq) * dq;
        dst[(c + 2) * HW] = truncf(v2 * iq) * dq;
        dst[(c + 3) * HW] = truncf(v3 * iq) * dq;
        dst[(c + 4) * HW] = truncf(v4 * iq) * dq;
        dst[(c + 5) * HW] = truncf(v5 * iq) * dq;
        dst[(c + 6) * HW] = truncf(v6 * iq) * dq;
        dst[(c + 7) * HW] = truncf(v7 * iq) * dq;
    }
}

extern "C" void kernel_launch(void* const* d_in, const int* in_sizes, int n_in,
                              void* d_out, int out_size, void* d_ws, size_t ws_size,
                              hipStream_t stream) {
    const float* in = (const float*)d_in[0];
    float* out      = (float*)d_out;
    float* ws       = (float*)d_ws;
    const int sites  = in_sizes[0] / C;   // 200704
    const int blocks = sites / 256;       // 784 (exact)

    if (ws_size >= (size_t)4 * sites * sizeof(float)) {
        dim3 g(blocks, 4);
        k_max<4><<<g, 256, 0, stream>>>(in, ws);
        k_quant<4><<<g, 256, 0, stream>>>(in, out, ws);
    } else if (ws_size >= (size_t)2 * sites * sizeof(float)) {
        dim3 g(blocks, 2);
        k_max<2><<<g, 256, 0, stream>>>(in, ws);
        k_quant<2><<<g, 256, 0, stream>>>(in, out, ws);
    } else {
        dim3 g(blocks, 1);
        k_max<1><<<g, 256, 0, stream>>>(in, ws);
        k_quant<1><<<g, 256, 0, stream>>>(in, out, ws);
    }
}

// Round 14
// 88.215 us; speedup vs baseline: 4.3124x; 1.2412x over previous
//
#include <hip/hip_runtime.h>
#include <cstdint>

// BFP quantize: block = channel vector at each (n,h,w), NCHW layout.
// N=64, C=256, H=W=56, mantissa_bits=3.
// delta = 2^(e-3), max_abs = m*2^e, m in [0.5,1) (frexp). q = trunc(x/delta)*delta.
// Exact pow2 arithmetic — absmax==0 verified R1..R13.
//
// R14: register-held single-pass at clean-geometry extreme.
// Regime data (13 rounds): serial strided template saturates ~3.5-4 TB/s at
// ANY wave count (R7 3.53 @3136w, R13 ~3.8 @12544w) — DRAM efficiency of
// interleaved stride-12544 small-chunk streams, not latency. Sequential
// streams hit 6.3-7 (fills/copy) but need 615 MB w/ re-read (~95us).
// Register-held single-pass moves only 411 MB (R6: 81.6us best, but 8x128B
// scattered instrs). This round: ONE contiguous 1024B run per wave-instruction
// (R1's proven-clean per-stream geometry), values retained in regs, no re-read.
// Block = 1024 thr (16 waves) on one 64-float4 window; wave w owns channels
// [16w,16w+16) — 16 consecutive planes per lane (page-local walk; the
// stride-interleaved walks R8/R9 were the catastrophic ones). 16 float4/lane
// = 64 data VGPR, semantically live until quantize (compiler can't serialize
// it away like R12's transient reduce). LDS 16KB combine, 1 barrier.
// 784 blocks x 16 waves = 12544 waves; ~16 waves/CU x 16 x 1KB = 256KB in
// flight/CU >> 90KB BDP.

constexpr int C    = 256;
constexpr int HW   = 56 * 56;    // 3136
constexpr int HW4  = HW / 4;     // 784 float4 per (n,c) plane
constexpr int CHW4 = C * HW4;    // float4 per image
constexpr int WCH  = 16;         // channels per wave (16 waves cover C=256)

__device__ __forceinline__ int fexp(float x) {
    int e;
    (void)frexpf(x, &e);         // v_frexp_exp_i32_f32; e=0 for x==0
    return e;
}

__device__ __forceinline__ void fmax4(float4& m, const float4& v) {
    m.x = fmaxf(m.x, fabsf(v.x));
    m.y = fmaxf(m.y, fabsf(v.y));
    m.z = fmaxf(m.z, fabsf(v.z));
    m.w = fmaxf(m.w, fabsf(v.w));
}

__global__ __launch_bounds__(1024, 4)
void bfp_kernel(const float4* __restrict__ in, float4* __restrict__ out) {
    const int lane = threadIdx.x & 63;
    const int w    = threadIdx.x >> 6;          // wave 0..15 = channel 16th
    const int sig  = blockIdx.x * 64 + lane;    // float4 site (64-f4 window)
    const int n    = sig / HW4;
    const int s4   = sig - n * HW4;

    const float4* p = in  + (size_t)n * CHW4 + (size_t)w * WCH * HW4 + s4;
    float4*       q = out + (size_t)n * CHW4 + (size_t)w * WCH * HW4 + s4;

    // ---- single read: 16 consecutive channels into registers ----
    // (each instruction: 64 lanes x 16B = ONE contiguous 1024B run)
    float4 v[WCH];
#pragma unroll
    for (int k = 0; k < WCH; ++k) v[k] = p[k * HW4];

    // ---- per-lane abs-max over the 16 held channels (4-acc tree) ----
    float4 a0 = make_float4(0.f, 0.f, 0.f, 0.f), a1 = a0, a2 = a0, a3 = a0;
#pragma unroll
    for (int k = 0; k < WCH; k += 4) {
        fmax4(a0, v[k + 0]); fmax4(a1, v[k + 1]);
        fmax4(a2, v[k + 2]); fmax4(a3, v[k + 3]);
    }
    float4 m;
    m.x = fmaxf(fmaxf(a0.x, a1.x), fmaxf(a2.x, a3.x));
    m.y = fmaxf(fmaxf(a0.y, a1.y), fmaxf(a2.y, a3.y));
    m.z = fmaxf(fmaxf(a0.z, a1.z), fmaxf(a2.z, a3.z));
    m.w = fmaxf(fmaxf(a0.w, a1.w), fmaxf(a2.w, a3.w));

    // ---- cross-wave combine: 16KB LDS, one barrier ----
    __shared__ float4 red[16][64];
    red[w][lane] = m;
    __syncthreads();
    float4 M = red[0][lane];
#pragma unroll
    for (int ww = 1; ww < 16; ++ww) fmax4(M, red[ww][lane]);  // vals >=0, fabs ok

    // ---- shared exponent -> delta = 2^(e-3), inv = 2^(3-e) (both exact) ----
    const int ex = fexp(M.x), ey = fexp(M.y), ez = fexp(M.z), ew = fexp(M.w);
    const float dx = ldexpf(1.f, ex - 3), ix = ldexpf(1.f, 3 - ex);
    const float dy = ldexpf(1.f, ey - 3), iy = ldexpf(1.f, 3 - ey);
    const float dz = ldexpf(1.f, ez - 3), iz = ldexpf(1.f, 3 - ez);
    const float dw = ldexpf(1.f, ew - 3), iw = ldexpf(1.f, 3 - ew);

    // ---- quantize from registers, store (1024B runs, single pass) ----
#pragma unroll
    for (int k = 0; k < WCH; ++k) {
        float4 r;
        r.x = truncf(v[k].x * ix) * dx;
        r.y = truncf(v[k].y * iy) * dy;
        r.z = truncf(v[k].z * iz) * dz;
        r.w = truncf(v[k].w * iw) * dw;
        q[k * HW4] = r;
    }
}

extern "C" void kernel_launch(void* const* d_in, const int* in_sizes, int n_in,
                              void* d_out, int out_size, void* d_ws, size_t ws_size,
                              hipStream_t stream) {
    const float* in = (const float*)d_in[0];
    float* out      = (float*)d_out;
    int total4 = in_sizes[0] / (4 * C);   // 50176 float4 sites
    int blocks = total4 / 64;             // 784 windows of 64 float4 (exact)
    bfp_kernel<<<blocks, 1024, 0, stream>>>((const float4*)in, (float4*)out);
}